// Round 9
// baseline (150.130 us; speedup 1.0000x reference)
//
#include <hip/hip_runtime.h>
#include <hip/hip_fp16.h>

#define KNB 31
#define CH 64
#define TEMP_INV 10.0f   // 1 / temperature(0.1)

typedef _Float16 h2 __attribute__((ext_vector_type(2)));
typedef float f2 __attribute__((ext_vector_type(2)));

// ---------------------------------------------------------------------------
// ws layout:
//   bytes [0, 16)    : double ws[2]  (sum(loss*mask), sum(mask))
//   bytes [16, 20)   : unsigned done-counter (last-block finalize)
//   bytes [256, ...) : fp8 feature table (N*64 B) | fp16 table (N*128 B)
// ---------------------------------------------------------------------------

__global__ void ch_init_ws(double* __restrict__ ws, unsigned* __restrict__ ctr) {
    ws[0] = 0.0;
    ws[1] = 0.0;
    *ctr  = 0u;
}

// features f32 -> fp8 e4m3 table (8 floats -> 8 bytes per thread); zeroes ws.
__global__ __launch_bounds__(256) void ch_cvt8(
    const float* __restrict__ in, unsigned char* __restrict__ out,
    double* __restrict__ ws, unsigned* __restrict__ ctr, int total8)
{
    const int idx = blockIdx.x * blockDim.x + threadIdx.x;
    if (idx == 0) { ws[0] = 0.0; ws[1] = 0.0; *ctr = 0u; }
    if (idx >= total8) return;
    const float4* ip = reinterpret_cast<const float4*>(in) + (size_t)idx * 2;
    const float4 a = ip[0];
    const float4 b = ip[1];
    unsigned lo = 0u, hi = 0u;
    lo = __builtin_amdgcn_cvt_pk_fp8_f32(a.x, a.y, lo, false);
    lo = __builtin_amdgcn_cvt_pk_fp8_f32(a.z, a.w, lo, true);
    hi = __builtin_amdgcn_cvt_pk_fp8_f32(b.x, b.y, hi, false);
    hi = __builtin_amdgcn_cvt_pk_fp8_f32(b.z, b.w, hi, true);
    uint2 o; o.x = lo; o.y = hi;
    reinterpret_cast<uint2*>(out)[idx] = o;
}

__device__ __forceinline__ void fp8_to_f32x16(const uint4 u, float* f) {
    union { uint4 v; unsigned w[4]; } U;
    U.v = u;
    #pragma unroll
    for (int q = 0; q < 4; ++q) {
        const f2 p0 = __builtin_amdgcn_cvt_pk_f32_fp8(U.w[q], false);
        const f2 p1 = __builtin_amdgcn_cvt_pk_f32_fp8(U.w[q], true);
        f[4 * q + 0] = p0[0]; f[4 * q + 1] = p0[1];
        f[4 * q + 2] = p1[0]; f[4 * q + 3] = p1[1];
    }
}

// fp8 main, 2 points per quad (i0 and i0+64): two independent online-softmax
// chains per lane double the loads in flight (Little's-law fix for the R8
// latency bind). Last block finalizes out[0].
__global__ __launch_bounds__(256, 4) void ch_main8q2(
    const unsigned char* __restrict__ tab8,   // (N, 64) fp8 e4m3
    const int*           __restrict__ labels, // (N,)
    const int*           __restrict__ nidx,   // (N, 31)
    double*              __restrict__ ws,
    unsigned*            __restrict__ ctr,
    float*               __restrict__ out,
    int n)
{
    const int t    = threadIdx.x;
    const int qid  = t >> 2;                  // quad id 0..63
    const int sub  = t & 3;
    const int i0   = blockIdx.x * 128 + qid;
    const int i1   = i0 + 64;
    const bool v0  = (i0 < n);
    const bool v1  = (i1 < n);
    const int i0c  = v0 ? i0 : 0;
    const int i1c  = v1 ? i1 : 0;

    float loss_w = 0.0f;
    float pm_f   = 0.0f;

    if (v0) {
        // own rows -> registers
        float fA0[16], fA1[16];
        fp8_to_f32x16(reinterpret_cast<const uint4*>(tab8 + (size_t)i0c * CH)[sub], fA0);
        fp8_to_f32x16(reinterpret_cast<const uint4*>(tab8 + (size_t)i1c * CH)[sub], fA1);

        const int lab0 = labels[i0c];
        const int lab1 = labels[i1c];
        const int* nrow0 = nidx + (size_t)i0c * KNB;
        const int* nrow1 = nidx + (size_t)i1c * KNB;

        float m0 = -1e30f, se0 = 0.0f, sp0 = 0.0f;
        float m1 = -1e30f, se1 = 0.0f, sp1 = 0.0f;
        int cnt0 = 0, cnt1 = 0;

        #pragma unroll 2
        for (int j = 0; j < KNB; ++j) {
            const int nj0 = nrow0[j];                    // quad-broadcast
            const int nj1 = nrow1[j];

            const uint4 b0 = reinterpret_cast<const uint4*>(tab8 + (size_t)nj0 * CH)[sub];
            const uint4 b1 = reinterpret_cast<const uint4*>(tab8 + (size_t)nj1 * CH)[sub];

            float fB[16];
            float s0 = 0.0f, s1 = 0.0f;
            fp8_to_f32x16(b0, fB);
            #pragma unroll
            for (int q = 0; q < 16; ++q) {
                const float d = fA0[q] - fB[q];
                s0 = fmaf(d, d, s0);
            }
            fp8_to_f32x16(b1, fB);
            #pragma unroll
            for (int q = 0; q < 16; ++q) {
                const float d = fA1[q] - fB[q];
                s1 = fmaf(d, d, s1);
            }

            s0 += __shfl_xor(s0, 1);
            s0 += __shfl_xor(s0, 2);
            s1 += __shfl_xor(s1, 1);
            s1 += __shfl_xor(s1, 2);

            const float l0 = -(sqrtf(s0) + 1e-8f);
            const float l1 = -(sqrtf(s1) + 1e-8f);

            const bool pm0 = (labels[nj0] == lab0);
            const bool pm1 = (labels[nj1] == lab1);
            cnt0 += pm0 ? 1 : 0;
            cnt1 += pm1 ? 1 : 0;

            if (l0 > m0) {
                const float r = __expf((m0 - l0) * TEMP_INV);
                se0 *= r; sp0 *= r; m0 = l0;
            }
            const float e0 = __expf((l0 - m0) * TEMP_INV);
            se0 += e0;
            if (pm0) sp0 += e0;

            if (l1 > m1) {
                const float r = __expf((m1 - l1) * TEMP_INV);
                se1 *= r; sp1 *= r; m1 = l1;
            }
            const float e1 = __expf((l1 - m1) * TEMP_INV);
            se1 += e1;
            if (pm1) sp1 += e1;
        }

        if (sub == 0) {
            if (v0 && cnt0 > 0 && cnt0 < KNB) {
                loss_w += -logf(sp0 / se0 + 1e-8f);
                pm_f   += 1.0f;
            }
            if (v1 && cnt1 > 0 && cnt1 < KNB) {
                loss_w += -logf(sp1 / se1 + 1e-8f);
                pm_f   += 1.0f;
            }
        }
    }

    // ---- block reduction, one double atomic per block; last block writes out
    __shared__ float s_l[256];
    __shared__ float s_c[256];
    s_l[t] = loss_w;
    s_c[t] = pm_f;
    __syncthreads();
    #pragma unroll
    for (int off = 128; off > 0; off >>= 1) {
        if (t < off) {
            s_l[t] += s_l[t + off];
            s_c[t] += s_c[t + off];
        }
        __syncthreads();
    }
    if (t == 0) {
        atomicAdd(ws,     (double)s_l[0]);
        atomicAdd(ws + 1, (double)s_c[0]);
        __threadfence();
        const unsigned old = atomicAdd(ctr, 1u);
        if (old == gridDim.x - 1) {
            const double sl = atomicAdd(ws, 0.0);
            const double sc = atomicAdd(ws + 1, 0.0);
            const double c  = (sc < 1.0) ? 1.0 : sc;
            out[0] = (float)(sl / c);   // WEIGHT = 1.0
        }
    }
}

// ---------------------------------------------------------------------------
// Fallback path (R2-exact, proven): fp16 table / f32 direct + separate finalize
// ---------------------------------------------------------------------------
__global__ __launch_bounds__(256) void ch_cvt(
    const float* __restrict__ in, __half* __restrict__ out, int total8)
{
    const int idx = blockIdx.x * blockDim.x + threadIdx.x;
    if (idx >= total8) return;
    const float4* ip = reinterpret_cast<const float4*>(in) + (size_t)idx * 2;
    const float4 a = ip[0];
    const float4 b = ip[1];
    union { uint4 u; __half2 h[4]; } o;
    o.h[0] = __floats2half2_rn(a.x, a.y);
    o.h[1] = __floats2half2_rn(a.z, a.w);
    o.h[2] = __floats2half2_rn(b.x, b.y);
    o.h[3] = __floats2half2_rn(b.z, b.w);
    reinterpret_cast<uint4*>(out)[idx] = o.u;
}

__device__ __forceinline__ float dot2acc(h2 d, float s) {
    return __builtin_amdgcn_fdot2(d, d, s, false);
}

template <bool FP16>
__global__ __launch_bounds__(256) void ch_main4(
    const float*  __restrict__ feat,
    const __half* __restrict__ tab,
    const int*    __restrict__ labels,
    const int*    __restrict__ nidx,
    double*       __restrict__ ws,
    int n)
{
    const int t   = threadIdx.x;
    const int i   = blockIdx.x * (256 / 4) + (t >> 2);
    const int sub = t & 3;

    float loss_w = 0.0f;
    float pm_f   = 0.0f;

    if (i < n) {
        float f[16];
        union { uint4 u[2]; h2 h[8]; } A;
        if constexpr (FP16) {
            const uint4* ap = reinterpret_cast<const uint4*>(tab + (size_t)i * CH + sub * 16);
            A.u[0] = ap[0];
            A.u[1] = ap[1];
        } else {
            const float4* ap = reinterpret_cast<const float4*>(feat + (size_t)i * CH + sub * 16);
            #pragma unroll
            for (int q = 0; q < 4; ++q) {
                const float4 v = ap[q];
                f[4 * q]     = v.x;
                f[4 * q + 1] = v.y;
                f[4 * q + 2] = v.z;
                f[4 * q + 3] = v.w;
            }
        }

        const int lab = labels[i];
        float m = -1e30f, se = 0.0f, sp = 0.0f;
        int cnt = 0;

        #pragma unroll 2
        for (int j = 0; j < KNB; ++j) {
            const int nj = nidx[(size_t)i * KNB + j];

            float s = 0.0f;
            if constexpr (FP16) {
                union { uint4 u[2]; h2 h[8]; } B;
                const uint4* bp = reinterpret_cast<const uint4*>(tab + (size_t)nj * CH + sub * 16);
                B.u[0] = bp[0];
                B.u[1] = bp[1];
                #pragma unroll
                for (int q = 0; q < 8; ++q) {
                    const h2 d = A.h[q] - B.h[q];
                    s = dot2acc(d, s);
                }
            } else {
                const float4* bp = reinterpret_cast<const float4*>(feat + (size_t)nj * CH + sub * 16);
                #pragma unroll
                for (int q = 0; q < 4; ++q) {
                    const float4 v = bp[q];
                    const float dx = f[4 * q]     - v.x;
                    const float dy = f[4 * q + 1] - v.y;
                    const float dz = f[4 * q + 2] - v.z;
                    const float dw = f[4 * q + 3] - v.w;
                    s += dx * dx + dy * dy + dz * dz + dw * dw;
                }
            }
            s += __shfl_xor(s, 1);
            s += __shfl_xor(s, 2);

            const float l = -(sqrtf(s) + 1e-8f);
            const bool pm = (labels[nj] == lab);
            cnt += pm ? 1 : 0;

            if (l > m) {
                const float r = __expf((m - l) * TEMP_INV);
                se *= r; sp *= r; m = l;
            }
            const float e = __expf((l - m) * TEMP_INV);
            se += e;
            if (pm) sp += e;
        }

        if (sub == 0 && cnt > 0 && cnt < KNB) {
            loss_w = -logf(sp / se + 1e-8f);
            pm_f   = 1.0f;
        }
    }

    __shared__ float s_l[256];
    __shared__ float s_c[256];
    s_l[t] = loss_w;
    s_c[t] = pm_f;
    __syncthreads();
    #pragma unroll
    for (int off = 128; off > 0; off >>= 1) {
        if (t < off) {
            s_l[t] += s_l[t + off];
            s_c[t] += s_c[t + off];
        }
        __syncthreads();
    }
    if (t == 0) {
        atomicAdd(ws,     (double)s_l[0]);
        atomicAdd(ws + 1, (double)s_c[0]);
    }
}

__global__ void ch_finalize(const double* __restrict__ ws, float* __restrict__ out) {
    double c = ws[1];
    if (c < 1.0) c = 1.0;
    out[0] = (float)(ws[0] / c);   // WEIGHT = 1.0
}

extern "C" void kernel_launch(void* const* d_in, const int* in_sizes, int n_in,
                              void* d_out, int out_size, void* d_ws, size_t ws_size,
                              hipStream_t stream) {
    const float* feat   = (const float*)d_in[0];
    const int*   labels = (const int*)d_in[1];
    const int*   nidx   = (const int*)d_in[2];
    float*       out    = (float*)d_out;
    double*      ws     = (double*)d_ws;
    unsigned*    ctr    = (unsigned*)((char*)d_ws + 16);

    const int n = in_sizes[1];                 // N = 100000
    const int total8 = n * CH / 8;

    if (ws_size >= 256 + (size_t)n * CH) {              // fp8 table: N*64 B
        unsigned char* tab = (unsigned char*)d_ws + 256;
        ch_cvt8<<<(total8 + 255) / 256, 256, 0, stream>>>(feat, tab, ws, ctr, total8);
        const int blocks = (n + 127) / 128;             // 128 points per block
        ch_main8q2<<<blocks, 256, 0, stream>>>(tab, labels, nidx, ws, ctr, out, n);
        return;
    }

    ch_init_ws<<<1, 1, 0, stream>>>(ws, ctr);
    const int blocks = (n + 63) / 64;
    if (ws_size >= 256 + (size_t)n * CH * 2) {          // fp16 table
        __half* tab = reinterpret_cast<__half*>((char*)d_ws + 256);
        ch_cvt<<<(total8 + 255) / 256, 256, 0, stream>>>(feat, tab, total8);
        ch_main4<true><<<blocks, 256, 0, stream>>>(feat, tab, labels, nidx, ws, n);
    } else {                                            // f32 direct
        ch_main4<false><<<blocks, 256, 0, stream>>>(feat, nullptr, labels, nidx, ws, n);
    }
    ch_finalize<<<1, 1, 0, stream>>>(ws, out);
}

// Round 10
// 83.315 us; speedup vs baseline: 1.8019x; 1.8019x over previous
//
#include <hip/hip_runtime.h>
#include <hip/hip_fp16.h>

#define KNB 31
#define CH 64
#define TEMP_INV 10.0f   // 1 / temperature(0.1)

typedef _Float16 h2 __attribute__((ext_vector_type(2)));
typedef float f2 __attribute__((ext_vector_type(2)));

// ---------------------------------------------------------------------------
// ws layout:
//   bytes [0, 16)    : double ws[2]  (sum(loss*mask), sum(mask))
//   bytes [16, 20)   : unsigned done-counter (last-block finalize)
//   bytes [256, ...) : fp8 feature table (N*64 B) | fp16 table (N*128 B)
// ---------------------------------------------------------------------------

__global__ void ch_init_ws(double* __restrict__ ws, unsigned* __restrict__ ctr) {
    ws[0] = 0.0;
    ws[1] = 0.0;
    *ctr  = 0u;
}

// features f32 -> fp8 e4m3 table (8 floats -> 8 bytes per thread); zeroes ws.
__global__ __launch_bounds__(256) void ch_cvt8(
    const float* __restrict__ in, unsigned char* __restrict__ out,
    double* __restrict__ ws, unsigned* __restrict__ ctr, int total8)
{
    const int idx = blockIdx.x * blockDim.x + threadIdx.x;
    if (idx == 0) { ws[0] = 0.0; ws[1] = 0.0; *ctr = 0u; }
    if (idx >= total8) return;
    const float4* ip = reinterpret_cast<const float4*>(in) + (size_t)idx * 2;
    const float4 a = ip[0];
    const float4 b = ip[1];
    unsigned lo = 0u, hi = 0u;
    lo = __builtin_amdgcn_cvt_pk_fp8_f32(a.x, a.y, lo, false);
    lo = __builtin_amdgcn_cvt_pk_fp8_f32(a.z, a.w, lo, true);
    hi = __builtin_amdgcn_cvt_pk_fp8_f32(b.x, b.y, hi, false);
    hi = __builtin_amdgcn_cvt_pk_fp8_f32(b.z, b.w, hi, true);
    uint2 o; o.x = lo; o.y = hi;
    reinterpret_cast<uint2*>(out)[idx] = o;
}

__device__ __forceinline__ void fp8_to_f32x16(const uint4 u, float* f) {
    union { uint4 v; unsigned w[4]; } U;
    U.v = u;
    #pragma unroll
    for (int q = 0; q < 4; ++q) {
        const f2 p0 = __builtin_amdgcn_cvt_pk_f32_fp8(U.w[q], false);
        const f2 p1 = __builtin_amdgcn_cvt_pk_f32_fp8(U.w[q], true);
        f[4 * q + 0] = p0[0]; f[4 * q + 1] = p0[1];
        f[4 * q + 2] = p1[0]; f[4 * q + 3] = p1[1];
    }
}

// decode-and-accumulate: no 16-float temp array (peak-pressure trim vs R9)
__device__ __forceinline__ float fp8_sub_sq_acc(const float* fA, const uint4 bu, float s) {
    union { uint4 v; unsigned w[4]; } U;
    U.v = bu;
    #pragma unroll
    for (int q = 0; q < 4; ++q) {
        const f2 p0 = __builtin_amdgcn_cvt_pk_f32_fp8(U.w[q], false);
        const f2 p1 = __builtin_amdgcn_cvt_pk_f32_fp8(U.w[q], true);
        float d;
        d = fA[4 * q + 0] - p0[0]; s = fmaf(d, d, s);
        d = fA[4 * q + 1] - p0[1]; s = fmaf(d, d, s);
        d = fA[4 * q + 2] - p1[0]; s = fmaf(d, d, s);
        d = fA[4 * q + 3] - p1[1]; s = fmaf(d, d, s);
    }
    return s;
}

// fp8 main, 2 points per quad (i0 and i0+64): two independent online-softmax
// chains per lane. amdgpu_waves_per_eu(2,4) raises the VGPR target to 128 so
// the ~90-reg working set does NOT spill (R9 lesson: launch_bounds alone
// leaves the allocator targeting 64 VGPR and spilling).
__global__ __launch_bounds__(256)
__attribute__((amdgpu_waves_per_eu(2, 4)))
void ch_main8q2(
    const unsigned char* __restrict__ tab8,   // (N, 64) fp8 e4m3
    const int*           __restrict__ labels, // (N,)
    const int*           __restrict__ nidx,   // (N, 31)
    double*              __restrict__ ws,
    unsigned*            __restrict__ ctr,
    float*               __restrict__ out,
    int n)
{
    const int t    = threadIdx.x;
    const int qid  = t >> 2;                  // quad id 0..63
    const int sub  = t & 3;
    const int i0   = blockIdx.x * 128 + qid;
    const int i1   = i0 + 64;
    const bool v0  = (i0 < n);
    const bool v1  = (i1 < n);
    const int i0c  = v0 ? i0 : 0;
    const int i1c  = v1 ? i1 : 0;

    float loss_w = 0.0f;
    float pm_f   = 0.0f;

    if (v0) {
        // own rows -> registers (decoded once, reused for all 31 neighbors)
        float fA0[16], fA1[16];
        fp8_to_f32x16(reinterpret_cast<const uint4*>(tab8 + (size_t)i0c * CH)[sub], fA0);
        fp8_to_f32x16(reinterpret_cast<const uint4*>(tab8 + (size_t)i1c * CH)[sub], fA1);

        const int lab0 = labels[i0c];
        const int lab1 = labels[i1c];
        const int* nrow0 = nidx + (size_t)i0c * KNB;
        const int* nrow1 = nidx + (size_t)i1c * KNB;

        float m0 = -1e30f, se0 = 0.0f, sp0 = 0.0f;
        float m1 = -1e30f, se1 = 0.0f, sp1 = 0.0f;
        int cnt0 = 0, cnt1 = 0;

        #pragma unroll 2
        for (int j = 0; j < KNB; ++j) {
            const int nj0 = nrow0[j];                    // quad-broadcast
            const int nj1 = nrow1[j];

            const uint4 b0 = reinterpret_cast<const uint4*>(tab8 + (size_t)nj0 * CH)[sub];
            const uint4 b1 = reinterpret_cast<const uint4*>(tab8 + (size_t)nj1 * CH)[sub];

            float s0 = fp8_sub_sq_acc(fA0, b0, 0.0f);
            float s1 = fp8_sub_sq_acc(fA1, b1, 0.0f);

            s0 += __shfl_xor(s0, 1);
            s0 += __shfl_xor(s0, 2);
            s1 += __shfl_xor(s1, 1);
            s1 += __shfl_xor(s1, 2);

            const float l0 = -(sqrtf(s0) + 1e-8f);
            const float l1 = -(sqrtf(s1) + 1e-8f);

            const bool pm0 = (labels[nj0] == lab0);
            const bool pm1 = (labels[nj1] == lab1);
            cnt0 += pm0 ? 1 : 0;
            cnt1 += pm1 ? 1 : 0;

            if (l0 > m0) {
                const float r = __expf((m0 - l0) * TEMP_INV);
                se0 *= r; sp0 *= r; m0 = l0;
            }
            const float e0 = __expf((l0 - m0) * TEMP_INV);
            se0 += e0;
            if (pm0) sp0 += e0;

            if (l1 > m1) {
                const float r = __expf((m1 - l1) * TEMP_INV);
                se1 *= r; sp1 *= r; m1 = l1;
            }
            const float e1 = __expf((l1 - m1) * TEMP_INV);
            se1 += e1;
            if (pm1) sp1 += e1;
        }

        if (sub == 0) {
            if (v0 && cnt0 > 0 && cnt0 < KNB) {
                loss_w += -logf(sp0 / se0 + 1e-8f);
                pm_f   += 1.0f;
            }
            if (v1 && cnt1 > 0 && cnt1 < KNB) {
                loss_w += -logf(sp1 / se1 + 1e-8f);
                pm_f   += 1.0f;
            }
        }
    }

    // ---- block reduction, one double atomic per block; last block writes out
    __shared__ float s_l[256];
    __shared__ float s_c[256];
    s_l[t] = loss_w;
    s_c[t] = pm_f;
    __syncthreads();
    #pragma unroll
    for (int off = 128; off > 0; off >>= 1) {
        if (t < off) {
            s_l[t] += s_l[t + off];
            s_c[t] += s_c[t + off];
        }
        __syncthreads();
    }
    if (t == 0) {
        atomicAdd(ws,     (double)s_l[0]);
        atomicAdd(ws + 1, (double)s_c[0]);
        __threadfence();
        const unsigned old = atomicAdd(ctr, 1u);
        if (old == gridDim.x - 1) {
            const double sl = atomicAdd(ws, 0.0);
            const double sc = atomicAdd(ws + 1, 0.0);
            const double c  = (sc < 1.0) ? 1.0 : sc;
            out[0] = (float)(sl / c);   // WEIGHT = 1.0
        }
    }
}

// ---------------------------------------------------------------------------
// Fallback path (R2-exact, proven): fp16 table / f32 direct + separate finalize
// ---------------------------------------------------------------------------
__global__ __launch_bounds__(256) void ch_cvt(
    const float* __restrict__ in, __half* __restrict__ out, int total8)
{
    const int idx = blockIdx.x * blockDim.x + threadIdx.x;
    if (idx >= total8) return;
    const float4* ip = reinterpret_cast<const float4*>(in) + (size_t)idx * 2;
    const float4 a = ip[0];
    const float4 b = ip[1];
    union { uint4 u; __half2 h[4]; } o;
    o.h[0] = __floats2half2_rn(a.x, a.y);
    o.h[1] = __floats2half2_rn(a.z, a.w);
    o.h[2] = __floats2half2_rn(b.x, b.y);
    o.h[3] = __floats2half2_rn(b.z, b.w);
    reinterpret_cast<uint4*>(out)[idx] = o.u;
}

__device__ __forceinline__ float dot2acc(h2 d, float s) {
    return __builtin_amdgcn_fdot2(d, d, s, false);
}

template <bool FP16>
__global__ __launch_bounds__(256) void ch_main4(
    const float*  __restrict__ feat,
    const __half* __restrict__ tab,
    const int*    __restrict__ labels,
    const int*    __restrict__ nidx,
    double*       __restrict__ ws,
    int n)
{
    const int t   = threadIdx.x;
    const int i   = blockIdx.x * (256 / 4) + (t >> 2);
    const int sub = t & 3;

    float loss_w = 0.0f;
    float pm_f   = 0.0f;

    if (i < n) {
        float f[16];
        union { uint4 u[2]; h2 h[8]; } A;
        if constexpr (FP16) {
            const uint4* ap = reinterpret_cast<const uint4*>(tab + (size_t)i * CH + sub * 16);
            A.u[0] = ap[0];
            A.u[1] = ap[1];
        } else {
            const float4* ap = reinterpret_cast<const float4*>(feat + (size_t)i * CH + sub * 16);
            #pragma unroll
            for (int q = 0; q < 4; ++q) {
                const float4 v = ap[q];
                f[4 * q]     = v.x;
                f[4 * q + 1] = v.y;
                f[4 * q + 2] = v.z;
                f[4 * q + 3] = v.w;
            }
        }

        const int lab = labels[i];
        float m = -1e30f, se = 0.0f, sp = 0.0f;
        int cnt = 0;

        #pragma unroll 2
        for (int j = 0; j < KNB; ++j) {
            const int nj = nidx[(size_t)i * KNB + j];

            float s = 0.0f;
            if constexpr (FP16) {
                union { uint4 u[2]; h2 h[8]; } B;
                const uint4* bp = reinterpret_cast<const uint4*>(tab + (size_t)nj * CH + sub * 16);
                B.u[0] = bp[0];
                B.u[1] = bp[1];
                #pragma unroll
                for (int q = 0; q < 8; ++q) {
                    const h2 d = A.h[q] - B.h[q];
                    s = dot2acc(d, s);
                }
            } else {
                const float4* bp = reinterpret_cast<const float4*>(feat + (size_t)nj * CH + sub * 16);
                #pragma unroll
                for (int q = 0; q < 4; ++q) {
                    const float4 v = bp[q];
                    const float dx = f[4 * q]     - v.x;
                    const float dy = f[4 * q + 1] - v.y;
                    const float dz = f[4 * q + 2] - v.z;
                    const float dw = f[4 * q + 3] - v.w;
                    s += dx * dx + dy * dy + dz * dz + dw * dw;
                }
            }
            s += __shfl_xor(s, 1);
            s += __shfl_xor(s, 2);

            const float l = -(sqrtf(s) + 1e-8f);
            const bool pm = (labels[nj] == lab);
            cnt += pm ? 1 : 0;

            if (l > m) {
                const float r = __expf((m - l) * TEMP_INV);
                se *= r; sp *= r; m = l;
            }
            const float e = __expf((l - m) * TEMP_INV);
            se += e;
            if (pm) sp += e;
        }

        if (sub == 0 && cnt > 0 && cnt < KNB) {
            loss_w = -logf(sp / se + 1e-8f);
            pm_f   = 1.0f;
        }
    }

    __shared__ float s_l[256];
    __shared__ float s_c[256];
    s_l[t] = loss_w;
    s_c[t] = pm_f;
    __syncthreads();
    #pragma unroll
    for (int off = 128; off > 0; off >>= 1) {
        if (t < off) {
            s_l[t] += s_l[t + off];
            s_c[t] += s_c[t + off];
        }
        __syncthreads();
    }
    if (t == 0) {
        atomicAdd(ws,     (double)s_l[0]);
        atomicAdd(ws + 1, (double)s_c[0]);
    }
}

__global__ void ch_finalize(const double* __restrict__ ws, float* __restrict__ out) {
    double c = ws[1];
    if (c < 1.0) c = 1.0;
    out[0] = (float)(ws[0] / c);   // WEIGHT = 1.0
}

extern "C" void kernel_launch(void* const* d_in, const int* in_sizes, int n_in,
                              void* d_out, int out_size, void* d_ws, size_t ws_size,
                              hipStream_t stream) {
    const float* feat   = (const float*)d_in[0];
    const int*   labels = (const int*)d_in[1];
    const int*   nidx   = (const int*)d_in[2];
    float*       out    = (float*)d_out;
    double*      ws     = (double*)d_ws;
    unsigned*    ctr    = (unsigned*)((char*)d_ws + 16);

    const int n = in_sizes[1];                 // N = 100000
    const int total8 = n * CH / 8;

    if (ws_size >= 256 + (size_t)n * CH) {              // fp8 table: N*64 B
        unsigned char* tab = (unsigned char*)d_ws + 256;
        ch_cvt8<<<(total8 + 255) / 256, 256, 0, stream>>>(feat, tab, ws, ctr, total8);
        const int blocks = (n + 127) / 128;             // 128 points per block
        ch_main8q2<<<blocks, 256, 0, stream>>>(tab, labels, nidx, ws, ctr, out, n);
        return;
    }

    ch_init_ws<<<1, 1, 0, stream>>>(ws, ctr);
    const int blocks = (n + 63) / 64;
    if (ws_size >= 256 + (size_t)n * CH * 2) {          // fp16 table
        __half* tab = reinterpret_cast<__half*>((char*)d_ws + 256);
        ch_cvt<<<(total8 + 255) / 256, 256, 0, stream>>>(feat, tab, total8);
        ch_main4<true><<<blocks, 256, 0, stream>>>(feat, tab, labels, nidx, ws, n);
    } else {                                            // f32 direct
        ch_main4<false><<<blocks, 256, 0, stream>>>(feat, nullptr, labels, nidx, ws, n);
    }
    ch_finalize<<<1, 1, 0, stream>>>(ws, out);
}